// Round 2
// 985.878 us; speedup vs baseline: 3.8859x; 3.8859x over previous
//
#include <hip/hip_runtime.h>

// GGLR — bf16-MFMA restructure, ws-footprint fixed to 14,680,064 B (proven size).
//   prep:    A fp32 -> Abf (bf16), ATbf (bf16 transpose), exact fp32 degrees
//   projb:   Wp/Wq projections (fp32 compute) -> TRANSPOSED bf16 [384][8192]
//   pq_mfma: p_k/q_k via mfma_f32_16x16x32_bf16, 128x128 tile, BK=64,
//            global_load_lds staging, 2-phase double-buffered loop
//   decb:    dec = p_k[2] @ Wd^T + bd -> bf16  (overwrites the degree slot)
//   eij:     e = (dec @ q2^T) * a*d^b*exp(c*d) via MFMA (K=128); q2 staged
//            from fp32 out_qk with in-register conversion (no q2b scratch)
// Scratch: Abf/ATbf live in the e_ij output region (written last).

constexpr int N_ = 8192;
constexpr int D_ = 128;

typedef __attribute__((ext_vector_type(8))) short bf16x8;   // 8 bf16 = 4 VGPR
typedef __attribute__((ext_vector_type(4))) float f32x4;

__device__ __forceinline__ unsigned short f2bf(float x) {
    unsigned int u = __float_as_uint(x);
    u += 0x7FFFu + ((u >> 16) & 1u);          // round-to-nearest-even
    return (unsigned short)(u >> 16);
}

#define GLDS16(g, l) __builtin_amdgcn_global_load_lds(                      \
        (__attribute__((address_space(1))) void*)(g),                       \
        (__attribute__((address_space(3))) void*)(l), 16, 0, 0)

// ---------------------------------------------------------------------------
// prep: A fp32 tile 128x128 -> Abf + ATbf (bf16), degrees via exact fp32 sums
// ---------------------------------------------------------------------------
__global__ __launch_bounds__(256) void prep_kernel(
    const float* __restrict__ A, unsigned short* __restrict__ Abf,
    unsigned short* __restrict__ ATbf, float* __restrict__ Dout,
    float* __restrict__ Din)
{
    __shared__ unsigned short tile[128][132];   // [j_local][i_local], pad 4
    __shared__ float degtmp[16][128];
    const int t  = threadIdx.x;
    const int i0 = blockIdx.y * 128;
    const int j0 = blockIdx.x * 128;
    const int rg = t >> 4;        // 0..15
    const int cg = t & 15;        // 0..15
    float cs[8] = {0.f,0.f,0.f,0.f,0.f,0.f,0.f,0.f};

#pragma unroll
    for (int ps = 0; ps < 8; ++ps) {
        const int row = ps * 16 + rg;
        const float* src = A + (size_t)(i0 + row) * N_ + j0 + cg * 8;
        float4 v0 = *(const float4*)src;
        float4 v1 = *(const float4*)(src + 4);
        float v[8] = {v0.x, v0.y, v0.z, v0.w, v1.x, v1.y, v1.z, v1.w};
        union { unsigned short us[8]; uint4 u; } pk;
        float rs = 0.f;
#pragma unroll
        for (int c = 0; c < 8; ++c) {
            pk.us[c] = f2bf(v[c]);
            rs += v[c];
            cs[c] += v[c];
            tile[cg * 8 + c][row] = pk.us[c];
        }
        *(uint4*)(Abf + (size_t)(i0 + row) * N_ + j0 + cg * 8) = pk.u;
        // row-sum over the 16 lanes sharing this row (xor masks stay in-group)
        rs += __shfl_xor(rs, 1);
        rs += __shfl_xor(rs, 2);
        rs += __shfl_xor(rs, 4);
        rs += __shfl_xor(rs, 8);
        if (cg == 0) atomicAdd(&Din[i0 + row], rs);
    }
#pragma unroll
    for (int c = 0; c < 8; ++c) degtmp[rg][cg * 8 + c] = cs[c];
    __syncthreads();
    if (t < 128) {
        float s = 0.f;
#pragma unroll
        for (int g = 0; g < 16; ++g) s += degtmp[g][t];
        atomicAdd(&Dout[j0 + t], s);
    }
    // transpose out: ATbf[j][i]
#pragma unroll
    for (int ps = 0; ps < 8; ++ps) {
        const int jr = ps * 16 + rg;
        uint2 w0 = *(const uint2*)&tile[jr][cg * 8];
        uint2 w1 = *(const uint2*)&tile[jr][cg * 8 + 4];
        unsigned short* dst = ATbf + (size_t)(j0 + jr) * N_ + i0 + cg * 8;
        *(uint2*)dst       = w0;
        *(uint2*)(dst + 4) = w1;
    }
}

// ---------------------------------------------------------------------------
// fp32 128x128x128 tile core: acc[rr][cc] = sum_d X[n0+ty*8+rr][d]*W[tx*8+cc][d]
// ---------------------------------------------------------------------------
__device__ __forceinline__ void gemm128_core(
    const float* __restrict__ X, const float* __restrict__ W,
    int n0, int t, float (&acc)[8][8],
    float (&XsT)[16][132], float (&WsT)[16][132])
{
    const int tx = t & 15;
    const int ty = t >> 4;
    for (int d0 = 0; d0 < 128; d0 += 16) {
        __syncthreads();
        const int r = t >> 1, c = t & 1;
        const float* sx = X + (size_t)(n0 + r) * 128 + d0 + c * 8;
        float4 v0 = *(const float4*)sx;
        float4 v1 = *(const float4*)(sx + 4);
        XsT[c*8+0][r] = v0.x; XsT[c*8+1][r] = v0.y; XsT[c*8+2][r] = v0.z; XsT[c*8+3][r] = v0.w;
        XsT[c*8+4][r] = v1.x; XsT[c*8+5][r] = v1.y; XsT[c*8+6][r] = v1.z; XsT[c*8+7][r] = v1.w;
        const float* sw = W + (size_t)r * 128 + d0 + c * 8;
        float4 w0 = *(const float4*)sw;
        float4 w1 = *(const float4*)(sw + 4);
        WsT[c*8+0][r] = w0.x; WsT[c*8+1][r] = w0.y; WsT[c*8+2][r] = w0.z; WsT[c*8+3][r] = w0.w;
        WsT[c*8+4][r] = w1.x; WsT[c*8+5][r] = w1.y; WsT[c*8+6][r] = w1.z; WsT[c*8+7][r] = w1.w;
        __syncthreads();
#pragma unroll
        for (int dd = 0; dd < 16; ++dd) {
            float xa[8], wb[8];
            *(float4*)&xa[0] = *(const float4*)&XsT[dd][ty*8];
            *(float4*)&xa[4] = *(const float4*)&XsT[dd][ty*8+4];
            *(float4*)&wb[0] = *(const float4*)&WsT[dd][tx*8];
            *(float4*)&wb[4] = *(const float4*)&WsT[dd][tx*8+4];
#pragma unroll
            for (int rr = 0; rr < 8; ++rr)
#pragma unroll
                for (int cc = 0; cc < 8; ++cc)
                    acc[rr][cc] += xa[rr] * wb[cc];
        }
    }
}

// ---------------------------------------------------------------------------
// projb: Wp/Wq = X @ Ws[k]^T + bs[k]  -> TRANSPOSED bf16 Out[k*128+e][i]
// ---------------------------------------------------------------------------
__global__ __launch_bounds__(256) void projb_kernel(
    const float* __restrict__ p, const float* __restrict__ q,
    const float* __restrict__ Ws, const float* __restrict__ bs,
    unsigned short* __restrict__ Wpt, unsigned short* __restrict__ Wqt)
{
    const int m = blockIdx.y;
    const int side = m / 3, k = m % 3;
    const float* X    = side ? q : p;
    const float* W    = Ws + (size_t)k * D_ * D_;
    const float* bias = bs + (size_t)k * D_;
    unsigned short* Out = side ? Wqt : Wpt;
    const int n0 = blockIdx.x * 128;

    __shared__ float XsT[16][132];
    __shared__ float WsT[16][132];
    __shared__ unsigned short trb[128][132];   // [e][i_local]

    const int t  = threadIdx.x;
    const int tx = t & 15;
    const int ty = t >> 4;
    float acc[8][8] = {};
    gemm128_core(X, W, n0, t, acc, XsT, WsT);

    float bv[8];
    *(float4*)&bv[0] = *(const float4*)&bias[tx*8];
    *(float4*)&bv[4] = *(const float4*)&bias[tx*8+4];
#pragma unroll
    for (int rr = 0; rr < 8; ++rr)
#pragma unroll
        for (int cc = 0; cc < 8; ++cc)
            trb[tx*8 + cc][ty*8 + rr] = f2bf(acc[rr][cc] + bv[cc]);
    __syncthreads();

    const int er = t >> 1, ec0 = (t & 1) * 64;
    unsigned short* dst = Out + (size_t)(k * 128 + er) * N_ + n0 + ec0;
#pragma unroll
    for (int c8 = 0; c8 < 64; c8 += 8) {
        uint2 w0 = *(const uint2*)&trb[er][ec0 + c8];
        uint2 w1 = *(const uint2*)&trb[er][ec0 + c8 + 4];
        *(uint2*)(dst + c8)     = w0;
        *(uint2*)(dst + c8 + 4) = w1;
    }
}

// ---------------------------------------------------------------------------
// decb: dec = p_k[2] @ Wd^T + bd  -> bf16 [8192][128]
// ---------------------------------------------------------------------------
__global__ __launch_bounds__(256) void decb_kernel(
    const float* __restrict__ pk2, const float* __restrict__ Wd,
    const float* __restrict__ bd, unsigned short* __restrict__ dec_b)
{
    __shared__ float XsT[16][132];
    __shared__ float WsT[16][132];
    const int t  = threadIdx.x;
    const int tx = t & 15;
    const int ty = t >> 4;
    const int n0 = blockIdx.x * 128;
    float acc[8][8] = {};
    gemm128_core(pk2, Wd, n0, t, acc, XsT, WsT);

    float bv[8];
    *(float4*)&bv[0] = *(const float4*)&bd[tx*8];
    *(float4*)&bv[4] = *(const float4*)&bd[tx*8+4];
#pragma unroll
    for (int rr = 0; rr < 8; ++rr) {
        union { unsigned short us[8]; uint4 u; } pk;
#pragma unroll
        for (int cc = 0; cc < 8; ++cc) pk.us[cc] = f2bf(acc[rr][cc] + bv[cc]);
        *(uint4*)(dec_b + (size_t)(n0 + ty*8 + rr) * D_ + tx*8) = pk.u;
    }
}

// ---------------------------------------------------------------------------
// pq_mfma: C[j, k*128+d] = sum_i X[j,i] * Wt[k*128+d, i]  (bf16 MFMA, fp32 acc)
// epilogue: /deg[j], leaky(0.01), fp32 out.
// 128x128 tile, BK=64, 4 waves (2x2) of 64x64, double-buffered gl_lds staging.
// ---------------------------------------------------------------------------
__device__ __forceinline__ void stage_pq(
    const unsigned short* __restrict__ X, const unsigned short* __restrict__ Wt,
    int j0, int t, size_t i0,
    unsigned short (&Xs)[128][64], unsigned short (&Wls)[128][64])
{
#pragma unroll
    for (int it = 0; it < 4; ++it) {
        const int ch = it * 256 + t;
        const int row = ch >> 3, ko = (ch & 7) * 8;
        GLDS16(X + (size_t)(j0 + row) * N_ + i0 + ko, &Xs[row][ko]);
    }
#pragma unroll
    for (int it = 0; it < 4; ++it) {
        const int ch = it * 256 + t;
        const int row = ch >> 3, ko = (ch & 7) * 8;
        GLDS16(Wt + (size_t)row * N_ + i0 + ko, &Wls[row][ko]);
    }
}

__global__ __launch_bounds__(256) void pq_mfma(
    const unsigned short* __restrict__ ATbf, const unsigned short* __restrict__ Abf,
    const unsigned short* __restrict__ Wpt, const unsigned short* __restrict__ Wqt,
    const float* __restrict__ Dout, const float* __restrict__ Din,
    float* __restrict__ out_pk, float* __restrict__ out_qk)
{
    const int j0   = blockIdx.x * 128;
    const int kk   = blockIdx.y;
    const int side = blockIdx.z;
    const unsigned short* X  = side ? Abf : ATbf;
    const unsigned short* Wt = (side ? Wqt : Wpt) + (size_t)kk * 128 * N_;
    const float* deg = side ? Din : Dout;
    float* outp = (side ? out_qk : out_pk) + (size_t)kk * N_ * D_;

    __shared__ unsigned short Xs[2][128][64];
    __shared__ unsigned short Wls[2][128][64];

    const int t   = threadIdx.x;
    const int l   = t & 63;
    const int wid = t >> 6;
    const int wm  = wid >> 1;      // m-half (64 rows)
    const int wn  = wid & 1;       // n-half (64 cols)
    const int lr  = l & 15;
    const int lk  = (l >> 4) * 8;

    f32x4 acc[4][4] = {};

    stage_pq(X, Wt, j0, t, 0, Xs[0], Wls[0]);
    __syncthreads();                       // compiler drains vmcnt before barrier
    const int NT = N_ / 64;                // 128 K-steps
    for (int ts = 0; ts < NT; ++ts) {
        const int cur = ts & 1;
        if (ts + 1 < NT)
            stage_pq(X, Wt, j0, t, (size_t)(ts + 1) * 64, Xs[cur ^ 1], Wls[cur ^ 1]);
#pragma unroll
        for (int ks = 0; ks < 2; ++ks) {
            bf16x8 av[4], bv[4];
#pragma unroll
            for (int mf = 0; mf < 4; ++mf)
                av[mf] = *(const bf16x8*)&Xs[cur][wm*64 + mf*16 + lr][ks*32 + lk];
#pragma unroll
            for (int nf = 0; nf < 4; ++nf)
                bv[nf] = *(const bf16x8*)&Wls[cur][wn*64 + nf*16 + lr][ks*32 + lk];
#pragma unroll
            for (int mf = 0; mf < 4; ++mf)
#pragma unroll
                for (int nf = 0; nf < 4; ++nf)
                    acc[mf][nf] = __builtin_amdgcn_mfma_f32_16x16x32_bf16(
                        av[mf], bv[nf], acc[mf][nf], 0, 0, 0);
        }
        __syncthreads();
    }

    const int lq = l >> 4;
#pragma unroll
    for (int mf = 0; mf < 4; ++mf) {
#pragma unroll
        for (int ri = 0; ri < 4; ++ri) {
            const int j = j0 + wm*64 + mf*16 + lq*4 + ri;
            const float dv = deg[j];
#pragma unroll
            for (int nf = 0; nf < 4; ++nf) {
                const int d = wn*64 + nf*16 + lr;
                float v = acc[mf][nf][ri] / dv;
                v = (v >= 0.f) ? v : 0.01f * v;
                outp[(size_t)j * D_ + d] = v;
            }
        }
    }
}

// ---------------------------------------------------------------------------
// eij: e[i,j] = (sum_d dec[i,d]*q2[j,d]) * a*d^b*exp(c*d)   (bf16 MFMA, K=128)
// dec staged bf16 via global_load_lds; q2 staged from fp32 out_qk + convert.
// ---------------------------------------------------------------------------
__global__ __launch_bounds__(256) void eij_mfma(
    const unsigned short* __restrict__ dec_b, const float* __restrict__ q2f,
    const float* __restrict__ dist, const float* __restrict__ pa,
    const float* __restrict__ pb, const float* __restrict__ pc,
    float* __restrict__ eout)
{
    const int i0 = blockIdx.y * 128;
    const int j0 = blockIdx.x * 128;
    __shared__ unsigned short Dsh[128][128];
    __shared__ unsigned short Qsh[128][128];
    const int t = threadIdx.x, l = t & 63;
    const int wid = t >> 6, wm = wid >> 1, wn = wid & 1;
    const int lr = l & 15, lk = (l >> 4) * 8;

    // dec tile: bf16 direct to LDS
#pragma unroll
    for (int it = 0; it < 8; ++it) {
        const int ch = it * 256 + t;
        const int row = ch >> 4, ko = (ch & 15) * 8;
        GLDS16(dec_b + (size_t)(i0 + row) * D_ + ko, &Dsh[row][ko]);
    }
    // q2 tile: fp32 -> bf16 in-register -> LDS
#pragma unroll
    for (int it = 0; it < 16; ++it) {
        const int ch = it * 256 + t;
        const int row = ch >> 5;          // 0..127
        const int c4  = (ch & 31) * 4;    // 0..124
        float4 v = *(const float4*)(q2f + (size_t)(j0 + row) * D_ + c4);
        union { unsigned short us[4]; uint2 u; } pk;
        pk.us[0] = f2bf(v.x); pk.us[1] = f2bf(v.y);
        pk.us[2] = f2bf(v.z); pk.us[3] = f2bf(v.w);
        *(uint2*)&Qsh[row][c4] = pk.u;
    }
    __syncthreads();

    f32x4 acc[4][4] = {};
#pragma unroll
    for (int ks = 0; ks < 4; ++ks) {
        bf16x8 av[4], bv[4];
#pragma unroll
        for (int mf = 0; mf < 4; ++mf)
            av[mf] = *(const bf16x8*)&Dsh[wm*64 + mf*16 + lr][ks*32 + lk];
#pragma unroll
        for (int nf = 0; nf < 4; ++nf)
            bv[nf] = *(const bf16x8*)&Qsh[wn*64 + nf*16 + lr][ks*32 + lk];
#pragma unroll
        for (int mf = 0; mf < 4; ++mf)
#pragma unroll
            for (int nf = 0; nf < 4; ++nf)
                acc[mf][nf] = __builtin_amdgcn_mfma_f32_16x16x32_bf16(
                    av[mf], bv[nf], acc[mf][nf], 0, 0, 0);
    }

    const float a_ = pa[0], b_ = pb[0], c_ = pc[0];
    const int lq = l >> 4;
#pragma unroll
    for (int mf = 0; mf < 4; ++mf) {
#pragma unroll
        for (int ri = 0; ri < 4; ++ri) {
            const int i = i0 + wm*64 + mf*16 + lq*4 + ri;
#pragma unroll
            for (int nf = 0; nf < 4; ++nf) {
                const int j = j0 + wn*64 + nf*16 + lr;
                const float d  = dist[(size_t)i * N_ + j];
                const float fx = a_ * __expf(b_ * __logf(d) + c_ * d);
                eout[(size_t)i * N_ + j] = acc[mf][nf][ri] * fx;
            }
        }
    }
}

// ---------------------------------------------------------------------------
extern "C" void kernel_launch(void* const* d_in, const int* in_sizes, int n_in,
                              void* d_out, int out_size, void* d_ws, size_t ws_size,
                              hipStream_t stream)
{
    (void)in_sizes; (void)n_in; (void)out_size; (void)ws_size;
    const float* p    = (const float*)d_in[0];
    const float* q    = (const float*)d_in[1];
    const float* A    = (const float*)d_in[2];
    const float* dist = (const float*)d_in[3];
    const float* Ws   = (const float*)d_in[4];
    const float* bs   = (const float*)d_in[5];
    const float* Wd   = (const float*)d_in[6];
    const float* bd   = (const float*)d_in[7];
    const float* pa   = (const float*)d_in[8];
    const float* pb   = (const float*)d_in[9];
    const float* pc   = (const float*)d_in[10];

    float* out    = (float*)d_out;
    float* out_pk = out;                              // [3,N,D]
    float* out_qk = out + (size_t)3 * N_ * D_;        // [3,N,D]
    float* out_e  = out + (size_t)6 * N_ * D_;        // [N,N]

    // ws layout — exactly 14,680,064 B (the proven workspace size):
    //   [0, 6291456)        Wpt  [384][8192] bf16
    //   [6291456, 12582912) Wqt  [384][8192] bf16
    //   [12582912, 14680064) dec_b [8192][128] bf16
    //     ... whose first 64 KiB doubles as Dout/Din (fp32 degrees):
    //     deg is consumed by pq_mfma BEFORE decb_kernel writes dec_b.
    char* w = (char*)d_ws;
    unsigned short* Wpt   = (unsigned short*)w;
    unsigned short* Wqt   = (unsigned short*)(w + 6291456);
    unsigned short* dec_b = (unsigned short*)(w + 12582912);
    float* Dout = (float*)(w + 12582912);
    float* Din  = Dout + N_;

    // bf16 A copies live in the e_ij output region (written last): 2*128MB = 256MB
    unsigned short* ATbf = (unsigned short*)out_e;                    // [N][N] = A^T
    unsigned short* Abf  = ATbf + (size_t)N_ * N_;                    // [N][N] = A

    hipMemsetAsync(Dout, 0, 2 * N_ * sizeof(float), stream);
    prep_kernel<<<dim3(64, 64), 256, 0, stream>>>(A, Abf, ATbf, Dout, Din);
    projb_kernel<<<dim3(64, 6), 256, 0, stream>>>(p, q, Ws, bs, Wpt, Wqt);
    pq_mfma<<<dim3(64, 3, 2), 256, 0, stream>>>(ATbf, Abf, Wpt, Wqt, Dout, Din,
                                                out_pk, out_qk);
    decb_kernel<<<dim3(64), 256, 0, stream>>>(out_pk + (size_t)2 * N_ * D_, Wd, bd, dec_b);
    eij_mfma<<<dim3(64, 64), 256, 0, stream>>>(dec_b, out_qk + (size_t)2 * N_ * D_,
                                               dist, pa, pb, pc, out_e);
}